// Round 2
// baseline (3035.485 us; speedup 1.0000x reference)
//
#include <hip/hip_runtime.h>

// Problem constants (B,C,H,W = 32,64,64,64; K=1024)
#define NPTS   131072      // B*H*W points
#define CDIM   64
#define KCODES 1024
#define HW     4096        // H*W
#define CHW    (CDIM*HW)   // 262144
#define NELEM  8388608     // B*C*H*W

// d_ws layout (floats): ws[0] = loss accumulator, ws[1..KCODES] = ||e_k||^2

__global__ void vq_prep(const float* __restrict__ emb, float* __restrict__ ws) {
    int k = blockIdx.x * blockDim.x + threadIdx.x;
    if (k == 0) ws[0] = 0.0f;                      // re-zero every launch (ws is poisoned)
    if (k < KCODES) {
        const float4* row = (const float4*)(emb + k * CDIM);
        double s = 0.0;                            // f64 accumulate → tighter norm
        #pragma unroll
        for (int i = 0; i < CDIM / 4; ++i) {
            float4 v = row[i];
            s += (double)v.x * v.x + (double)v.y * v.y
               + (double)v.z * v.z + (double)v.w * v.w;
        }
        ws[1 + k] = (float)s;
    }
}

__global__ __launch_bounds__(256, 4) void vq_main(
    const float* __restrict__ x,
    const float* __restrict__ emb,
    const float* __restrict__ norms,    // = ws+1
    float*       __restrict__ loss_acc, // = ws
    float*       __restrict__ out)
{
    const int n  = blockIdx.x * 256 + threadIdx.x;   // point id, grid covers exactly NPTS
    const int b  = n >> 12;                          // n / HW
    const int sp = n & (HW - 1);                     // n % HW
    const float* xp = x + b * CHW + sp;

    // Load this point's 64 channels into registers (coalesced across lanes per c).
    float z[CDIM];
    #pragma unroll
    for (int c = 0; c < CDIM; ++c) z[c] = xp[c * HW];

    const float4* E4 = (const float4*)emb;           // [KCODES][16] float4 rows

    float best   = 3.4e38f;
    float second = 3.4e38f;
    int   bidx   = 0;

    for (int k0 = 0; k0 < KCODES; k0 += 4) {
        float d0 = 0.f, d1 = 0.f, d2 = 0.f, d3 = 0.f;
        #pragma unroll
        for (int c4 = 0; c4 < CDIM / 4; ++c4) {
            // Wave-uniform addresses: every lane reads the same e values.
            float4 e0 = E4[(k0 + 0) * 16 + c4];
            float4 e1 = E4[(k0 + 1) * 16 + c4];
            float4 e2 = E4[(k0 + 2) * 16 + c4];
            float4 e3 = E4[(k0 + 3) * 16 + c4];
            float z0 = z[c4 * 4 + 0], z1 = z[c4 * 4 + 1];
            float z2 = z[c4 * 4 + 2], z3 = z[c4 * 4 + 3];
            d0 += e0.x * z0 + e0.y * z1 + e0.z * z2 + e0.w * z3;
            d1 += e1.x * z0 + e1.y * z1 + e1.z * z2 + e1.w * z3;
            d2 += e2.x * z0 + e2.y * z1 + e2.z * z2 + e2.w * z3;
            d3 += e3.x * z0 + e3.y * z1 + e3.z * z2 + e3.w * z3;
        }
        // score = ||e||^2 - 2*z.e  (argmin-equivalent to full distance)
        float s0 = norms[k0 + 0] - 2.0f * d0;
        float s1 = norms[k0 + 1] - 2.0f * d1;
        float s2 = norms[k0 + 2] - 2.0f * d2;
        float s3 = norms[k0 + 3] - 2.0f * d3;
        // strict < keeps the FIRST index on ties, matching jnp.argmin.
        // Track best AND second-best for tie detection.
        if (s0 < best) { second = best; best = s0; bidx = k0 + 0; } else if (s0 < second) second = s0;
        if (s1 < best) { second = best; best = s1; bidx = k0 + 1; } else if (s1 < second) second = s1;
        if (s2 < best) { second = best; best = s2; bidx = k0 + 2; } else if (s2 < second) second = s2;
        if (s3 < best) { second = best; best = s3; bidx = k0 + 3; } else if (s3 < second) second = s3;
    }

    // Near-tie: f32 rounding (worst ~1e-3) could have flipped the argmin.
    // Re-scan the whole codebook in f64 to get the TRUE argmin. Rare
    // (~1e-3 of points), so the masked-wave cost is small.
    if (second - best < 1e-2f) {
        double bb = 1e300;
        int    bi = 0;
        for (int k = 0; k < KCODES; ++k) {
            const float4* row = E4 + k * 16;
            double s = 0.0;
            #pragma unroll
            for (int c4 = 0; c4 < CDIM / 4; ++c4) {
                float4 e = row[c4];
                double t0 = (double)z[c4 * 4 + 0] - (double)e.x;
                double t1 = (double)z[c4 * 4 + 1] - (double)e.y;
                double t2 = (double)z[c4 * 4 + 2] - (double)e.z;
                double t3 = (double)z[c4 * 4 + 3] - (double)e.w;
                s += t0 * t0 + t1 * t1 + t2 * t2 + t3 * t3;
            }
            if (s < bb) { bb = s; bi = k; }   // strict <, first index on ties
        }
        bidx = bi;
    }

    // Gather chosen code, write quantized_st (== quantized numerically), accumulate MSE.
    const float4* Q4 = (const float4*)(emb + bidx * CDIM);
    float* op = out + 1 + b * CHW + sp;
    float lsum = 0.0f;
    #pragma unroll
    for (int c4 = 0; c4 < CDIM / 4; ++c4) {
        float4 q = Q4[c4];
        float d;
        d = q.x - z[c4 * 4 + 0]; lsum += d * d; op[(c4 * 4 + 0) * HW] = q.x;
        d = q.y - z[c4 * 4 + 1]; lsum += d * d; op[(c4 * 4 + 1) * HW] = q.y;
        d = q.z - z[c4 * 4 + 2]; lsum += d * d; op[(c4 * 4 + 2) * HW] = q.z;
        d = q.w - z[c4 * 4 + 3]; lsum += d * d; op[(c4 * 4 + 3) * HW] = q.w;
    }

    // indices output (stored as float; harness reads whole buffer as f32)
    out[1 + NELEM + n] = (float)bidx;

    // wave-level reduction of loss partial, one atomic per wave
    #pragma unroll
    for (int off = 32; off > 0; off >>= 1)
        lsum += __shfl_down(lsum, off, 64);
    if ((threadIdx.x & 63) == 0)
        atomicAdd(loss_acc, lsum);
}

__global__ void vq_final(const float* __restrict__ ws, float* __restrict__ out) {
    if (threadIdx.x == 0 && blockIdx.x == 0)
        out[0] = 0.25f * ws[0] / (float)NELEM;
}

extern "C" void kernel_launch(void* const* d_in, const int* in_sizes, int n_in,
                              void* d_out, int out_size, void* d_ws, size_t ws_size,
                              hipStream_t stream) {
    const float* x   = (const float*)d_in[0];
    const float* emb = (const float*)d_in[1];
    float* out = (float*)d_out;
    float* ws  = (float*)d_ws;

    vq_prep<<<(KCODES + 255) / 256, 256, 0, stream>>>(emb, ws);
    vq_main<<<NPTS / 256, 256, 0, stream>>>(x, emb, ws + 1, ws, out);
    vq_final<<<1, 64, 0, stream>>>(ws, out);
}

// Round 3
// 218.526 us; speedup vs baseline: 13.8907x; 13.8907x over previous
//
#include <hip/hip_runtime.h>

// Problem constants (B,C,H,W = 32,64,64,64; K=1024)
#define NPTS   131072      // B*H*W points
#define CDIM   64
#define KCODES 1024
#define HW     4096        // H*W
#define CHW    (CDIM*HW)   // 262144
#define NELEM  8388608     // B*C*H*W

#define FLAG_THR 2.5e-2f   // flag if (second-best) below this; > 2x worst-case bf16-split err
#define WLCAP    32768
#define NFB_WAVES 1024

typedef __attribute__((ext_vector_type(8))) short bf16x8;   // 8 bf16 (4 VGPRs)
typedef __attribute__((ext_vector_type(4))) float f32x4;

// ws layout:
//   float ws[0]            : loss accumulator
//   float ws[8..8+1023]    : ||e_k||^2 (f32, f64-accumulated)
//   ushort ehi[1024*64]    : bf16 hi of codebook   (byte off 4128, 16B aligned)
//   ushort elo[1024*64]    : bf16 lo of codebook
//   int    wl_cnt          : worklist counter
//   int    wl[WLCAP]       : worklist of flagged point ids
#define WS_NORM_OFF 8
#define WS_EHI_OFF  (8 + KCODES)                     // in floats

__device__ inline unsigned short f32_to_bf16_rn(float f) {
    unsigned u = __builtin_bit_cast(unsigned, f);
    unsigned r = (u + 0x7FFFu + ((u >> 16) & 1u)) >> 16;
    return (unsigned short)r;
}
__device__ inline float bf16_to_f32(unsigned short h) {
    unsigned u = ((unsigned)h) << 16;
    return __builtin_bit_cast(float, u);
}

__global__ void vq_prep(const float* __restrict__ emb, float* __restrict__ ws) {
    int k = blockIdx.x * 256 + threadIdx.x;          // grid 4x256 = 1024
    float* norms = ws + WS_NORM_OFF;
    unsigned short* ehi = (unsigned short*)(ws + WS_EHI_OFF);
    unsigned short* elo = ehi + KCODES * CDIM;
    int* wl_cnt = (int*)(elo + KCODES * CDIM);
    if (k == 0) { ws[0] = 0.0f; *wl_cnt = 0; }
    if (k < KCODES) {
        const float4* row = (const float4*)(emb + k * CDIM);
        double s = 0.0;
        #pragma unroll
        for (int c4 = 0; c4 < CDIM / 4; ++c4) {
            float4 v = row[c4];
            s += (double)v.x * v.x + (double)v.y * v.y
               + (double)v.z * v.z + (double)v.w * v.w;
            float vv[4] = {v.x, v.y, v.z, v.w};
            #pragma unroll
            for (int t = 0; t < 4; ++t) {
                unsigned short hi = f32_to_bf16_rn(vv[t]);
                float hif = bf16_to_f32(hi);
                unsigned short lo = f32_to_bf16_rn(vv[t] - hif);
                ehi[k * CDIM + c4 * 4 + t] = hi;
                elo[k * CDIM + c4 * 4 + t] = lo;
            }
        }
        norms[k] = (float)s;
    }
}

// 256 threads = 4 waves; each wave owns 64 consecutive points (4 MFMA M-subtiles).
__global__ __launch_bounds__(256) void vq_main(
    const float* __restrict__ x,
    const float* __restrict__ emb,
    float* __restrict__ ws,
    float* __restrict__ out)
{
    const float* norms = ws + WS_NORM_OFF;
    const unsigned short* ehi = (const unsigned short*)(ws + WS_EHI_OFF);
    const unsigned short* elo = ehi + KCODES * CDIM;
    int* wl_cnt = (int*)(elo + KCODES * CDIM);
    int* wl = wl_cnt + 16;

    const int lane = threadIdx.x & 63;
    const int widx = threadIdx.x >> 6;
    const int wb   = (blockIdx.x * 4 + widx) * 64;   // wave's first point
    const int lrow = lane & 15;                      // A row / B col / C col lane field
    const int lk   = lane >> 4;                      // k-octet lane field

    __shared__ int   s_idx[4][64];
    __shared__ float s_gap[4][64];

    // ---- A fragments: (-2x) split to bf16 hi/lo, 4 subtiles x 2 K-halves ----
    bf16x8 ahi[4][2], alo[4][2];
    #pragma unroll
    for (int m = 0; m < 4; ++m) {
        int p = wb + m * 16 + lrow;
        const float* xb = x + (p >> 12) * CHW + (p & (HW - 1));
        #pragma unroll
        for (int h = 0; h < 2; ++h) {
            #pragma unroll
            for (int j = 0; j < 8; ++j) {
                int c = h * 32 + lk * 8 + j;
                float v = -2.0f * xb[c * HW];        // fold -2 into A (exact scale)
                unsigned short hi = f32_to_bf16_rn(v);
                float hif = bf16_to_f32(hi);
                unsigned short lo = f32_to_bf16_rn(v - hif);
                ahi[m][h][j] = (short)hi;
                alo[m][h][j] = (short)lo;
            }
        }
    }

    // ---- running (best, second, idx) per accumulator slot ----
    float best[4][4], sec[4][4];
    int   bidx[4][4];
    #pragma unroll
    for (int m = 0; m < 4; ++m)
        #pragma unroll
        for (int r = 0; r < 4; ++r) { best[m][r] = 3.4e38f; sec[m][r] = 3.4e38f; bidx[m][r] = 0; }

    for (int n0 = 0; n0 < KCODES; n0 += 16) {
        const int code = n0 + lrow;
        const unsigned short* eh = ehi + code * CDIM + lk * 8;
        const unsigned short* el = elo + code * CDIM + lk * 8;
        bf16x8 bh0 = *(const bf16x8*)(eh);
        bf16x8 bh1 = *(const bf16x8*)(eh + 32);
        bf16x8 bl0 = *(const bf16x8*)(el);
        bf16x8 bl1 = *(const bf16x8*)(el + 32);
        float nrm = norms[code];

        f32x4 acc[4];
        #pragma unroll
        for (int m = 0; m < 4; ++m) acc[m] = (f32x4){nrm, nrm, nrm, nrm};  // seed with ||e||^2
        // score = ||e||^2 + (-2z).e ; 3-term bf16 split (hh + lh + hl)
        #pragma unroll
        for (int m = 0; m < 4; ++m) acc[m] = __builtin_amdgcn_mfma_f32_16x16x32_bf16(ahi[m][0], bh0, acc[m], 0, 0, 0);
        #pragma unroll
        for (int m = 0; m < 4; ++m) acc[m] = __builtin_amdgcn_mfma_f32_16x16x32_bf16(ahi[m][1], bh1, acc[m], 0, 0, 0);
        #pragma unroll
        for (int m = 0; m < 4; ++m) acc[m] = __builtin_amdgcn_mfma_f32_16x16x32_bf16(alo[m][0], bh0, acc[m], 0, 0, 0);
        #pragma unroll
        for (int m = 0; m < 4; ++m) acc[m] = __builtin_amdgcn_mfma_f32_16x16x32_bf16(alo[m][1], bh1, acc[m], 0, 0, 0);
        #pragma unroll
        for (int m = 0; m < 4; ++m) acc[m] = __builtin_amdgcn_mfma_f32_16x16x32_bf16(ahi[m][0], bl0, acc[m], 0, 0, 0);
        #pragma unroll
        for (int m = 0; m < 4; ++m) acc[m] = __builtin_amdgcn_mfma_f32_16x16x32_bf16(ahi[m][1], bl1, acc[m], 0, 0, 0);

        #pragma unroll
        for (int m = 0; m < 4; ++m) {
            #pragma unroll
            for (int r = 0; r < 4; ++r) {
                float sc = acc[m][r];
                bool  lt = sc < best[m][r];
                float ns = fminf(sec[m][r], sc);
                sec[m][r]  = lt ? best[m][r] : ns;
                best[m][r] = lt ? sc : best[m][r];
                bidx[m][r] = lt ? code : bidx[m][r];
            }
        }
    }

    // ---- reduce over the 16 col-lanes (low 4 lane bits); lexicographic ties ----
    #pragma unroll
    for (int m = 0; m < 4; ++m) {
        #pragma unroll
        for (int r = 0; r < 4; ++r) {
            float b_ = best[m][r], s_ = sec[m][r];
            int   i_ = bidx[m][r];
            #pragma unroll
            for (int msk = 1; msk < 16; msk <<= 1) {
                float ob = __shfl_xor(b_, msk, 64);
                float os = __shfl_xor(s_, msk, 64);
                int   oi = __shfl_xor(i_, msk, 64);
                float nsec = fminf(fminf(s_, os), fmaxf(b_, ob));
                bool take = (ob < b_) || (ob == b_ && oi < i_);
                b_ = take ? ob : b_;
                i_ = take ? oi : i_;
                s_ = nsec;
            }
            if (lrow == 0) {
                int pl = m * 16 + lk * 4 + r;        // point local to wave (C-row mapping)
                s_idx[widx][pl] = i_;
                s_gap[widx][pl] = s_ - b_;
            }
        }
    }
    __syncthreads();

    // ---- epilogue: 1 lane = 1 point ----
    const int p = wb + lane;
    const int myidx = s_idx[widx][lane];
    const float gap = s_gap[widx][lane];
    if (gap < FLAG_THR) {
        int slot = atomicAdd(wl_cnt, 1);
        if (slot < WLCAP) wl[slot] = p;
    }
    out[1 + NELEM + p] = (float)myidx;

    const int b = p >> 12, sp = p & (HW - 1);
    const float*  xr   = x + b * CHW + sp;
    float*        orow = out + 1 + b * CHW + sp;
    const float4* er   = (const float4*)(emb + myidx * CDIM);
    float lsum = 0.0f;
    #pragma unroll
    for (int c4 = 0; c4 < CDIM / 4; ++c4) {
        float4 q = er[c4];
        float qq[4] = {q.x, q.y, q.z, q.w};
        #pragma unroll
        for (int t = 0; t < 4; ++t) {
            int c = c4 * 4 + t;
            float xv = xr[c * HW];
            float d = qq[t] - xv;
            lsum += d * d;
            orow[c * HW] = qq[t];
        }
    }
    #pragma unroll
    for (int off = 32; off > 0; off >>= 1)
        lsum += __shfl_down(lsum, off, 64);
    if (lane == 0) atomicAdd(ws, lsum);
}

// One wave per flagged point: exact f64 rescan; patch idx/quantized/loss if changed.
__global__ __launch_bounds__(256) void vq_fallback(
    const float* __restrict__ x,
    const float* __restrict__ emb,
    float* __restrict__ ws,
    float* __restrict__ out)
{
    const unsigned short* ehi = (const unsigned short*)(ws + WS_EHI_OFF);
    const unsigned short* elo = ehi + KCODES * CDIM;
    const int* wl_cnt = (const int*)(elo + KCODES * CDIM);
    const int* wl = wl_cnt + 16;

    const int lane = threadIdx.x & 63;
    const int slot = blockIdx.x * 4 + (threadIdx.x >> 6);
    int cnt = *wl_cnt;
    if (cnt > WLCAP) cnt = WLCAP;

    for (int i = slot; i < cnt; i += NFB_WAVES) {
        const int p = wl[i];
        const int b = p >> 12, sp = p & (HW - 1);
        const float* xr = x + b * CHW + sp;
        float z[CDIM];
        #pragma unroll
        for (int c = 0; c < CDIM; ++c) z[c] = xr[c * HW];   // wave-uniform addrs

        double bd = 1e300;
        int    bi = 0;
        for (int kk = 0; kk < 16; ++kk) {
            int k = kk * 64 + lane;
            const float4* er = (const float4*)(emb + k * CDIM);
            double s = 0.0;
            #pragma unroll
            for (int c4 = 0; c4 < CDIM / 4; ++c4) {
                float4 e = er[c4];
                double t0 = (double)z[c4 * 4 + 0] - (double)e.x;
                double t1 = (double)z[c4 * 4 + 1] - (double)e.y;
                double t2 = (double)z[c4 * 4 + 2] - (double)e.z;
                double t3 = (double)z[c4 * 4 + 3] - (double)e.w;
                s += t0 * t0 + t1 * t1 + t2 * t2 + t3 * t3;
            }
            if (s < bd) { bd = s; bi = k; }                  // ascending k -> first idx
        }
        #pragma unroll
        for (int msk = 1; msk < 64; msk <<= 1) {
            double od = __shfl_xor(bd, msk, 64);
            int    oi = __shfl_xor(bi, msk, 64);
            bool take = (od < bd) || (od == bd && oi < bi);
            bd = take ? od : bd;
            bi = take ? oi : bi;
        }
        const int oldidx = (int)out[1 + NELEM + p];
        if (bi != oldidx) {
            if (lane == 0) out[1 + NELEM + p] = (float)bi;
            float xv = xr[lane * HW];
            float qn = emb[bi * CDIM + lane];
            float qo = emb[oldidx * CDIM + lane];
            out[1 + b * CHW + lane * HW + sp] = qn;
            float dl = (qn - xv) * (qn - xv) - (qo - xv) * (qo - xv);
            #pragma unroll
            for (int off = 32; off > 0; off >>= 1)
                dl += __shfl_down(dl, off, 64);
            if (lane == 0) atomicAdd(ws, dl);
        }
    }
}

__global__ void vq_final(const float* __restrict__ ws, float* __restrict__ out) {
    if (threadIdx.x == 0 && blockIdx.x == 0)
        out[0] = 0.25f * ws[0] / (float)NELEM;
}

extern "C" void kernel_launch(void* const* d_in, const int* in_sizes, int n_in,
                              void* d_out, int out_size, void* d_ws, size_t ws_size,
                              hipStream_t stream) {
    const float* x   = (const float*)d_in[0];
    const float* emb = (const float*)d_in[1];
    float* out = (float*)d_out;
    float* ws  = (float*)d_ws;

    vq_prep<<<4, 256, 0, stream>>>(emb, ws);
    vq_main<<<NPTS / 256, 256, 0, stream>>>(x, emb, ws, out);
    vq_fallback<<<NFB_WAVES / 4, 256, 0, stream>>>(x, emb, ws, out);
    vq_final<<<1, 64, 0, stream>>>(ws, out);
}